// Round 1
// baseline (2099.829 us; speedup 1.0000x reference)
//
#include <hip/hip_runtime.h>

#define NTOK 49
#define DIM 384
#define HEADS 12
#define HD 32
#define SCALE 0.17677669529663687f

typedef __attribute__((ext_vector_type(8))) short bf16x8;
typedef __attribute__((ext_vector_type(4))) float f32x4;

#define MFMA16(a, b, c) __builtin_amdgcn_mfma_f32_16x16x32_bf16((a), (b), (c), 0, 0, 0)

__device__ __forceinline__ short f2bf(float f) {
  union { float f; unsigned u; } v; v.f = f;
  unsigned r = (v.u + 0x7FFFu + ((v.u >> 16) & 1u)) >> 16;
  return (short)(unsigned short)r;
}

// ws layout:
//   wqT  : short [384][384]      elem off 0
//   wkvT : short [768][384]      elem off 147456   (rows 0-383 = K, 384-767 = V)
//   wpT  : short [384][384]      elem off 442368
//   biasx: float [12][49][49]    byte off 1179648
#define WQT_OFF   0
#define WKVT_OFF  147456
#define WPT_OFF   442368
#define BIAS_BYTE_OFF 1179648

__global__ void prep_kernel(const float* __restrict__ qw, const float* __restrict__ kvw,
                            const float* __restrict__ pw, const float* __restrict__ bt,
                            short* __restrict__ wsS, float* __restrict__ biasx) {
  int id = blockIdx.x * 256 + threadIdx.x;
  const int SZ1 = 384 * 384;          // wqT
  const int SZ2 = 768 * 384;          // wkvT
  const int SZ3 = 384 * 384;          // wpT
  if (id < SZ1) {
    int n = id / 384, k = id % 384;
    wsS[WQT_OFF + id] = f2bf(qw[k * 384 + n]);
  } else if (id < SZ1 + SZ2) {
    int t = id - SZ1; int n = t / 384, k = t % 384;
    wsS[WKVT_OFF + t] = f2bf(kvw[k * 768 + n]);
  } else if (id < SZ1 + SZ2 + SZ3) {
    int t = id - (SZ1 + SZ2); int n = t / 384, k = t % 384;
    wsS[WPT_OFF + t] = f2bf(pw[k * 384 + n]);
  } else if (id < SZ1 + SZ2 + SZ3 + HEADS * NTOK * NTOK) {
    int t = id - (SZ1 + SZ2 + SZ3);
    int h = t / (NTOK * NTOK); int rc = t % (NTOK * NTOK);
    int r = rc / NTOK, c = rc % NTOK;
    int idx = ((r / 7 - c / 7) + 6) * 13 + ((r % 7 - c % 7) + 6);
    biasx[t] = bt[idx * HEADS + h];
  }
}

// LDS element offsets (shorts). Row strides: 16B-aligned, != 0 mod 64 elems
// so wave64 ds_read_b128 fragments spread across all 32 banks.
#define XE_OFF   0            // [49][392]
#define XB_OFF   19208        // [49][392]
#define OUT_OFF  38416        // [49][392]
#define QH_OFF   57624        // [64][72]  (2 heads x 32 cols + pad)
#define KH_OFF   62232        // [64][72]
#define VT_OFF   66840        // [64][72]  V^T: [dim][token]
#define PS_OFF   71448        // [64][72]  P (bf16 probs), cols = key index
#define LDS_ELEMS 76056
#define LDS_BYTES (LDS_ELEMS * 2)   // 152112

__global__ __launch_bounds__(256, 1)
void fused_kernel(const float* __restrict__ xe, const float* __restrict__ xb,
                  const float* __restrict__ qb, const float* __restrict__ kvb,
                  const float* __restrict__ pb,
                  const short* __restrict__ wqT, const short* __restrict__ wkvT,
                  const short* __restrict__ wpT, const float* __restrict__ biasx,
                  float* __restrict__ out) {
  extern __shared__ short lds[];
  short* XE  = lds + XE_OFF;
  short* XB  = lds + XB_OFF;
  short* OUTB = lds + OUT_OFF;
  short* QH2 = lds + QH_OFF;
  short* KH2 = lds + KH_OFF;
  short* VT2 = lds + VT_OFF;
  short* PS  = lds + PS_OFF;

  const int b   = blockIdx.x;
  const int tid = threadIdx.x;
  const int w   = tid >> 6;        // wave 0..3
  const int l   = tid & 63;
  const int m16 = l & 15;
  const int g   = l >> 4;          // 0..3

  // ---- stage x_edge / x_body into LDS as bf16 ----
  const float* xew = xe + (size_t)b * (NTOK * DIM);
  const float* xbw = xb + (size_t)b * (NTOK * DIM);
  for (int i4 = tid; i4 < NTOK * DIM / 4; i4 += 256) {
    int e = i4 * 4;
    int r = e / DIM, c = e % DIM;
    float4 ve = *(const float4*)(xew + e);
    float4 vb = *(const float4*)(xbw + e);
    short* pe = &XE[r * 392 + c];
    pe[0] = f2bf(ve.x); pe[1] = f2bf(ve.y); pe[2] = f2bf(ve.z); pe[3] = f2bf(ve.w);
    short* pbp = &XB[r * 392 + c];
    pbp[0] = f2bf(vb.x); pbp[1] = f2bf(vb.y); pbp[2] = f2bf(vb.z); pbp[3] = f2bf(vb.w);
  }
  // zero V^T pad tokens 49..63 (kept zero forever; V writes are guarded)
  for (int i = tid; i < 64 * 15; i += 256) {
    int d = i / 15, t = 49 + i % 15;
    VT2[d * 72 + t] = 0;
  }
  __syncthreads();

  const int rowA = (w * 16 + m16 < 48) ? (w * 16 + m16) : 48;  // clamped A row (unused pad rows dup row 48)
  const f32x4 zf = {0.f, 0.f, 0.f, 0.f};

  // ================= head-pair loop =================
  for (int j = 0; j < HEADS / 2; ++j) {
    const int h0 = 2 * j;
    // ---- Phase A: Q,K,V GEMMs for heads h0,h0+1.
    // wave w owns one 16-wide N-column of each of Q,K,V (unique B-frags per wave).
    const int hw  = h0 + (w >> 1);
    const int ntw = (w & 1);
    const int ncol = hw * 32 + ntw * 16;           // global n within 384
    const short* bqp = wqT  + (size_t)ncol * 384;
    const short* bkp = wkvT + (size_t)ncol * 384;
    const short* bvp = wkvT + (size_t)(384 + ncol) * 384;

    f32x4 qa[4], ka[4], va[4];
#pragma unroll
    for (int m = 0; m < 4; ++m) { qa[m] = zf; ka[m] = zf; va[m] = zf; }

#pragma unroll
    for (int kk = 0; kk < 12; ++kk) {
      const int ko = kk * 32 + g * 8;
      bf16x8 fbq = *(const bf16x8*)(bqp + m16 * 384 + ko);
      bf16x8 fbk = *(const bf16x8*)(bkp + m16 * 384 + ko);
      bf16x8 fbv = *(const bf16x8*)(bvp + m16 * 384 + ko);
#pragma unroll
      for (int m = 0; m < 4; ++m) {
        int ar = (m * 16 + m16 < 48) ? (m * 16 + m16) : 48;
        bf16x8 ae = *(const bf16x8*)(&XE[ar * 392 + ko]);
        bf16x8 ab = *(const bf16x8*)(&XB[ar * 392 + ko]);
        qa[m] = MFMA16(ae, fbq, qa[m]);
        ka[m] = MFMA16(ab, fbk, ka[m]);
        va[m] = MFMA16(ab, fbv, va[m]);
      }
    }
    // epilogue: add biases, write bf16 tiles. local col in pair buffers = w*16+m16
    {
      const float qbv = qb[ncol + m16];
      const float kbv = kvb[ncol + m16];
      const float vbv = kvb[384 + ncol + m16];
      const int cl = w * 16 + m16;
#pragma unroll
      for (int m = 0; m < 4; ++m) {
#pragma unroll
        for (int i = 0; i < 4; ++i) {
          int r = m * 16 + g * 4 + i;
          QH2[r * 72 + cl] = f2bf(qa[m][i] + qbv);
          KH2[r * 72 + cl] = f2bf(ka[m][i] + kbv);
          if (r < 49) VT2[cl * 72 + r] = f2bf(va[m][i] + vbv);
        }
      }
    }
    __syncthreads();

    // ---- Phase B: attention for each head of the pair; wave w owns query rows w*16..w*16+15
    for (int hl = 0; hl < 2; ++hl) {
      const int hg = h0 + hl;
      // S = Q @ K^T  (rows = queries, cols = keys), K-dim = 32
      bf16x8 aq = *(const bf16x8*)(&QH2[(w * 16 + m16) * 72 + hl * 32 + g * 8]);
      f32x4 s[4];
#pragma unroll
      for (int t = 0; t < 4; ++t) {
        bf16x8 bk = *(const bf16x8*)(&KH2[(t * 16 + m16) * 72 + hl * 32 + g * 8]);
        s[t] = MFMA16(aq, bk, zf);
      }
      // softmax over cols (49 real, rest masked); row = w*16 + g*4 + i held across 16 lanes
#pragma unroll
      for (int i = 0; i < 4; ++i) {
        const int row = w * 16 + g * 4 + i;
        float sv[4];
#pragma unroll
        for (int t = 0; t < 4; ++t) {
          int c = t * 16 + m16;
          sv[t] = (row < 49 && c < 49)
                      ? s[t][i] * SCALE + biasx[(hg * NTOK + row) * NTOK + c]
                      : -INFINITY;
        }
        float mx = fmaxf(fmaxf(sv[0], sv[1]), fmaxf(sv[2], sv[3]));
#pragma unroll
        for (int d = 1; d < 16; d <<= 1) mx = fmaxf(mx, __shfl_xor(mx, d, 16));
        float e0 = __expf(sv[0] - mx), e1 = __expf(sv[1] - mx);
        float e2 = __expf(sv[2] - mx), e3 = __expf(sv[3] - mx);
        float sum = e0 + e1 + e2 + e3;
#pragma unroll
        for (int d = 1; d < 16; d <<= 1) sum += __shfl_xor(sum, d, 16);
        float inv = 1.0f / sum;
        PS[row * 72 +  0 + m16] = f2bf(e0 * inv);
        PS[row * 72 + 16 + m16] = f2bf(e1 * inv);
        PS[row * 72 + 32 + m16] = f2bf(e2 * inv);
        PS[row * 72 + 48 + m16] = f2bf(e3 * inv);
      }
      __syncthreads();

      // O = P @ V  (K-dim 64, N = 32)
      f32x4 o0 = zf, o1 = zf;
#pragma unroll
      for (int ks = 0; ks < 2; ++ks) {
        bf16x8 ap = *(const bf16x8*)(&PS[(w * 16 + m16) * 72 + ks * 32 + g * 8]);
        bf16x8 b0 = *(const bf16x8*)(&VT2[(hl * 32 + m16) * 72 + ks * 32 + g * 8]);
        bf16x8 b1 = *(const bf16x8*)(&VT2[(hl * 32 + 16 + m16) * 72 + ks * 32 + g * 8]);
        o0 = MFMA16(ap, b0, o0);
        o1 = MFMA16(ap, b1, o1);
      }
#pragma unroll
      for (int i = 0; i < 4; ++i) {
        int r = w * 16 + g * 4 + i;
        if (r < 49) {
          OUTB[r * 392 + hg * 32 + m16]      = f2bf(o0[i]);
          OUTB[r * 392 + hg * 32 + 16 + m16] = f2bf(o1[i]);
        }
      }
      __syncthreads();
    }
  }

  // ================= out-projection: OUTB[49x384] @ WpT + pb =================
  // wave w owns N-tile columns {w, w+4, ..., w+20}; all 4 M-tiles.
  f32x4 acc[6][4];
#pragma unroll
  for (int c = 0; c < 6; ++c)
#pragma unroll
    for (int m = 0; m < 4; ++m) acc[c][m] = zf;

#pragma unroll
  for (int kk = 0; kk < 12; ++kk) {
    const int ko = kk * 32 + g * 8;
    bf16x8 af[4];
#pragma unroll
    for (int m = 0; m < 4; ++m) {
      int ar = (m * 16 + m16 < 48) ? (m * 16 + m16) : 48;
      af[m] = *(const bf16x8*)(&OUTB[ar * 392 + ko]);
    }
#pragma unroll
    for (int c = 0; c < 6; ++c) {
      int nt = w + c * 4;
      bf16x8 bw = *(const bf16x8*)(wpT + (size_t)(nt * 16 + m16) * 384 + ko);
#pragma unroll
      for (int m = 0; m < 4; ++m) acc[c][m] = MFMA16(af[m], bw, acc[c][m]);
    }
  }
  float* outw = out + (size_t)b * (NTOK * DIM);
#pragma unroll
  for (int c = 0; c < 6; ++c) {
    int col = (w + c * 4) * 16 + m16;
    float pbv = pb[col];
#pragma unroll
    for (int m = 0; m < 4; ++m) {
#pragma unroll
      for (int i = 0; i < 4; ++i) {
        int r = m * 16 + g * 4 + i;
        if (r < 49) outw[r * DIM + col] = acc[c][m][i] + pbv;
      }
    }
  }
}

extern "C" void kernel_launch(void* const* d_in, const int* in_sizes, int n_in,
                              void* d_out, int out_size, void* d_ws, size_t ws_size,
                              hipStream_t stream) {
  const float* xe  = (const float*)d_in[0];
  const float* xb  = (const float*)d_in[1];
  const float* qw  = (const float*)d_in[2];
  const float* qb  = (const float*)d_in[3];
  const float* kvw = (const float*)d_in[4];
  const float* kvb = (const float*)d_in[5];
  const float* pw  = (const float*)d_in[6];
  const float* pb  = (const float*)d_in[7];
  const float* bt  = (const float*)d_in[8];
  float* out = (float*)d_out;
  short* wsS = (short*)d_ws;
  float* biasx = (float*)((char*)d_ws + BIAS_BYTE_OFF);

  const int nwin = in_sizes[0] / (NTOK * DIM);

  const int prep_items = 384 * 384 + 768 * 384 + 384 * 384 + HEADS * NTOK * NTOK;
  prep_kernel<<<(prep_items + 255) / 256, 256, 0, stream>>>(qw, kvw, pw, bt, wsS, biasx);

  hipFuncSetAttribute((const void*)fused_kernel,
                      hipFuncAttributeMaxDynamicSharedMemorySize, LDS_BYTES);
  fused_kernel<<<nwin, 256, LDS_BYTES, stream>>>(
      xe, xb, qb, kvb, pb,
      wsS + WQT_OFF, wsS + WKVT_OFF, wsS + WPT_OFF, biasx, out);
}

// Round 2
// 1607.372 us; speedup vs baseline: 1.3064x; 1.3064x over previous
//
#include <hip/hip_runtime.h>

#define NTOK 49
#define DIM 384
#define HEADS 12
#define SCALE 0.17677669529663687f

typedef __attribute__((ext_vector_type(8))) short bf16x8;
typedef __attribute__((ext_vector_type(4))) float f32x4;

#define MFMA16(a, b, c) __builtin_amdgcn_mfma_f32_16x16x32_bf16((a), (b), (c), 0, 0, 0)

__device__ __forceinline__ short f2bf(float f) {
  union { float f; unsigned u; } v; v.f = f;
  unsigned r = (v.u + 0x7FFFu + ((v.u >> 16) & 1u)) >> 16;
  return (short)(unsigned short)r;
}

// ws layout:
//   wqT  : short [384][384]      elem off 0
//   wkvT : short [768][384]      elem off 147456   (rows 0-383 = K, 384-767 = V)
//   wpT  : short [384][384]      elem off 442368
//   biasx: float [12][49][49]    byte off 1179648
#define WQT_OFF   0
#define WKVT_OFF  147456
#define WPT_OFF   442368
#define BIAS_BYTE_OFF 1179648

__global__ void prep_kernel(const float* __restrict__ qw, const float* __restrict__ kvw,
                            const float* __restrict__ pw, const float* __restrict__ bt,
                            short* __restrict__ wsS, float* __restrict__ biasx) {
  int id = blockIdx.x * 256 + threadIdx.x;
  const int SZ1 = 384 * 384;
  const int SZ2 = 768 * 384;
  const int SZ3 = 384 * 384;
  if (id < SZ1) {
    int n = id / 384, k = id % 384;
    wsS[WQT_OFF + id] = f2bf(qw[k * 384 + n]);
  } else if (id < SZ1 + SZ2) {
    int t = id - SZ1; int n = t / 384, k = t % 384;
    wsS[WKVT_OFF + t] = f2bf(kvw[k * 768 + n]);
  } else if (id < SZ1 + SZ2 + SZ3) {
    int t = id - (SZ1 + SZ2); int n = t / 384, k = t % 384;
    wsS[WPT_OFF + t] = f2bf(pw[k * 384 + n]);
  } else if (id < SZ1 + SZ2 + SZ3 + HEADS * NTOK * NTOK) {
    int t = id - (SZ1 + SZ2 + SZ3);
    int h = t / (NTOK * NTOK); int rc = t % (NTOK * NTOK);
    int r = rc / NTOK, c = rc % NTOK;
    int idx = ((r / 7 - c / 7) + 6) * 13 + ((r % 7 - c % 7) + 6);
    biasx[t] = bt[idx * HEADS + h];
  }
}

// LDS (shorts). Strides: 392(=196dw), 216(=108dw), 72(=36dw), 40(=20dw)
// all ≡ 4·odd mod 32 dwords -> ≤2-way bank aliasing for 16-lane frag reads.
#define X_OFF    0            // [49][392]  x (edge, then body)
#define QH6_OFF  19208        // [64][216]  Q transit (3 pairs); aliases KQH/VT2/PS
#define KQH_OFF  19208        // [64][72]
#define VT_OFF   23816        // [64][72]   V^T per pair: [dim][token]
#define PS_OFF   28424        // [64][72]   P probs (bf16)
#define OH_OFF   33032        // [64][40]   per-head O tile
#define LDS_ELEMS 35592
#define LDS_BYTES (LDS_ELEMS * 2)   // 71184 -> 2 blocks/CU

__global__ __launch_bounds__(256, 2)
void fused_kernel(const float* __restrict__ xe, const float* __restrict__ xb,
                  const float* __restrict__ qb, const float* __restrict__ kvb,
                  const float* __restrict__ pb,
                  const short* __restrict__ wqT, const short* __restrict__ wkvT,
                  const short* __restrict__ wpT, const float* __restrict__ biasx,
                  float* __restrict__ out) {
  extern __shared__ short lds[];
  short* X   = lds + X_OFF;
  short* QH6 = lds + QH6_OFF;
  short* KQH = lds + KQH_OFF;
  short* VT2 = lds + VT_OFF;
  short* PS  = lds + PS_OFF;
  short* OH  = lds + OH_OFF;

  const int b   = blockIdx.x;
  const int tid = threadIdx.x;
  const int w   = tid >> 6;
  const int l   = tid & 63;
  const int m16 = l & 15;
  const int g   = l >> 4;

  const f32x4 zf = {0.f, 0.f, 0.f, 0.f};

  // ---- stage x_edge into X (bf16) ----
  const float* xew = xe + (size_t)b * (NTOK * DIM);
  for (int i4 = tid; i4 < NTOK * DIM / 4; i4 += 256) {
    int e = i4 * 4;
    int r = e / DIM, c = e % DIM;
    float4 v = *(const float4*)(xew + e);
    short* p = &X[r * 392 + c];
    p[0] = f2bf(v.x); p[1] = f2bf(v.y); p[2] = f2bf(v.z); p[3] = f2bf(v.w);
  }
  __syncthreads();

  // ================= Phase 1: Q for all heads, frags -> registers =================
  bf16x8 qf[12];
#pragma unroll
  for (int t = 0; t < 2; ++t) {
    f32x4 qacc[3][4];
#pragma unroll
    for (int u = 0; u < 3; ++u)
#pragma unroll
      for (int m = 0; m < 4; ++m) qacc[u][m] = zf;

    const short* wq = wqT + (size_t)(t * 192) * 384;
#pragma unroll
    for (int kk = 0; kk < 12; ++kk) {
      const int ko = kk * 32 + g * 8;
      bf16x8 ax[4];
#pragma unroll
      for (int m = 0; m < 4; ++m) {
        int ar = m * 16 + m16; ar = ar < 49 ? ar : 48;
        ax[m] = *(const bf16x8*)(&X[ar * 392 + ko]);
      }
#pragma unroll
      for (int u = 0; u < 3; ++u) {
        int nt = w + 4 * u;
        bf16x8 bw = *(const bf16x8*)(wq + (size_t)(nt * 16 + m16) * 384 + ko);
#pragma unroll
        for (int m = 0; m < 4; ++m) qacc[u][m] = MFMA16(ax[m], bw, qacc[u][m]);
      }
    }
    __syncthreads();   // prior mega-iter's qf reads done before overwrite
#pragma unroll
    for (int u = 0; u < 3; ++u) {
      int cl = (w + 4 * u) * 16 + m16;
      float qbv = qb[t * 192 + cl];
#pragma unroll
      for (int m = 0; m < 4; ++m)
#pragma unroll
        for (int i = 0; i < 4; ++i) {
          int r = m * 16 + g * 4 + i;
          QH6[r * 216 + cl] = f2bf((qacc[u][m][i] + qbv) * SCALE);
        }
    }
    __syncthreads();
#pragma unroll
    for (int hh = 0; hh < 6; ++hh)
      qf[t * 6 + hh] = *(const bf16x8*)(&QH6[(w * 16 + m16) * 216 + hh * 32 + g * 8]);
  }
  __syncthreads();   // qf reads done; QH6 region + X free

  // ---- stage x_body over X; zero V^T pad tokens ----
  const float* xbw = xb + (size_t)b * (NTOK * DIM);
  for (int i4 = tid; i4 < NTOK * DIM / 4; i4 += 256) {
    int e = i4 * 4;
    int r = e / DIM, c = e % DIM;
    float4 v = *(const float4*)(xbw + e);
    short* p = &X[r * 392 + c];
    p[0] = f2bf(v.x); p[1] = f2bf(v.y); p[2] = f2bf(v.z); p[3] = f2bf(v.w);
  }
  for (int i = tid; i < 64 * 23; i += 256) {
    int d = i / 23, c = 49 + i % 23;
    VT2[d * 72 + c] = 0;
  }
  __syncthreads();

  // ================= Phase 3: per pair KV-GEMM + attention + fused out-proj =======
  f32x4 acc[24];
#pragma unroll
  for (int c = 0; c < 24; ++c) acc[c] = zf;

#pragma unroll
  for (int j = 0; j < 6; ++j) {
    // ---- K,V GEMM: wave w owns cols j*64 + w*16 .. +15 ----
    f32x4 ka[4], va[4];
#pragma unroll
    for (int m = 0; m < 4; ++m) { ka[m] = zf; va[m] = zf; }
    const short* bk = wkvT + (size_t)(j * 64 + w * 16) * 384;
    const short* bv = wkvT + (size_t)(384 + j * 64 + w * 16) * 384;
#pragma unroll
    for (int kk = 0; kk < 12; ++kk) {
      const int ko = kk * 32 + g * 8;
      bf16x8 fk = *(const bf16x8*)(bk + (size_t)m16 * 384 + ko);
      bf16x8 fv = *(const bf16x8*)(bv + (size_t)m16 * 384 + ko);
#pragma unroll
      for (int m = 0; m < 4; ++m) {
        int ar = m * 16 + m16; ar = ar < 49 ? ar : 48;
        bf16x8 ax = *(const bf16x8*)(&X[ar * 392 + ko]);
        ka[m] = MFMA16(ax, fk, ka[m]);
        va[m] = MFMA16(ax, fv, va[m]);
      }
    }
    __syncthreads();   // prior pair's attention reads of KQH/VT2 done
    {
      const float kbv = kvb[j * 64 + w * 16 + m16];
      const float vbv = kvb[384 + j * 64 + w * 16 + m16];
      const int cl = w * 16 + m16;
#pragma unroll
      for (int m = 0; m < 4; ++m)
#pragma unroll
        for (int i = 0; i < 4; ++i) {
          int r = m * 16 + g * 4 + i;
          KQH[r * 72 + cl] = f2bf(ka[m][i] + kbv);
          if (r < 49) VT2[cl * 72 + r] = f2bf(va[m][i] + vbv);
        }
    }
    __syncthreads();

    // ---- attention, both heads of the pair; P/O are wave-local rows ----
#pragma unroll
    for (int hl = 0; hl < 2; ++hl) {
      const int h = 2 * j + hl;
      // bias prefetch (clamped addresses, masked later)
      float bv4[4][4];
#pragma unroll
      for (int i = 0; i < 4; ++i) {
        int row = w * 16 + g * 4 + i; row = row < 49 ? row : 48;
#pragma unroll
        for (int t = 0; t < 4; ++t) {
          int c = t * 16 + m16; c = c < 49 ? c : 48;
          bv4[i][t] = biasx[(h * NTOK + row) * NTOK + c];
        }
      }
      // S = Q K^T (scale pre-folded into qf)
      f32x4 s[4];
#pragma unroll
      for (int t = 0; t < 4; ++t) {
        bf16x8 bkf = *(const bf16x8*)(&KQH[(t * 16 + m16) * 72 + hl * 32 + g * 8]);
        s[t] = MFMA16(qf[h], bkf, zf);
      }
      // softmax (rows w*16+g*4+i, 16 lanes hold 4 cols each)
#pragma unroll
      for (int i = 0; i < 4; ++i) {
        const int row = w * 16 + g * 4 + i;
        float sv[4];
#pragma unroll
        for (int t = 0; t < 4; ++t) {
          int c = t * 16 + m16;
          sv[t] = (row < 49 && c < 49) ? s[t][i] + bv4[i][t] : -INFINITY;
        }
        float mx = fmaxf(fmaxf(sv[0], sv[1]), fmaxf(sv[2], sv[3]));
#pragma unroll
        for (int d = 1; d < 16; d <<= 1) mx = fmaxf(mx, __shfl_xor(mx, d, 16));
        float mxr = fmaxf(mx, -3.0e38f);   // keep pad rows NaN-free
        float e0 = __expf(sv[0] - mxr), e1 = __expf(sv[1] - mxr);
        float e2 = __expf(sv[2] - mxr), e3 = __expf(sv[3] - mxr);
        float sum = e0 + e1 + e2 + e3;
#pragma unroll
        for (int d = 1; d < 16; d <<= 1) sum += __shfl_xor(sum, d, 16);
        float inv = (row < 49) ? 1.0f / sum : 0.0f;
        PS[row * 72 +  0 + m16] = f2bf(e0 * inv);
        PS[row * 72 + 16 + m16] = f2bf(e1 * inv);
        PS[row * 72 + 32 + m16] = f2bf(e2 * inv);
        PS[row * 72 + 48 + m16] = f2bf(e3 * inv);
      }
      asm volatile("s_waitcnt lgkmcnt(0)" ::: "memory");
      __builtin_amdgcn_sched_barrier(0);

      // O = P V  (wave-local rows; pad keys have P=0 and V=0)
      f32x4 o0 = zf, o1 = zf;
#pragma unroll
      for (int ks = 0; ks < 2; ++ks) {
        bf16x8 ap = *(const bf16x8*)(&PS[(w * 16 + m16) * 72 + ks * 32 + g * 8]);
        bf16x8 b0 = *(const bf16x8*)(&VT2[(hl * 32 + m16) * 72 + ks * 32 + g * 8]);
        bf16x8 b1 = *(const bf16x8*)(&VT2[(hl * 32 + 16 + m16) * 72 + ks * 32 + g * 8]);
        o0 = MFMA16(ap, b0, o0);
        o1 = MFMA16(ap, b1, o1);
      }
#pragma unroll
      for (int i = 0; i < 4; ++i) {
        int r = w * 16 + g * 4 + i;
        OH[r * 40 + m16]      = f2bf(o0[i]);
        OH[r * 40 + 16 + m16] = f2bf(o1[i]);
      }
      asm volatile("s_waitcnt lgkmcnt(0)" ::: "memory");
      __builtin_amdgcn_sched_barrier(0);

      // fused out-projection: acc[c] += O_h(rows of this wave) * Wp[h*32..][c*16..]
      bf16x8 af = *(const bf16x8*)(&OH[(w * 16 + m16) * 40 + g * 8]);
#pragma unroll
      for (int c = 0; c < 24; ++c) {
        bf16x8 bwp = *(const bf16x8*)(wpT + (size_t)(c * 16 + m16) * 384 + h * 32 + g * 8);
        acc[c] = MFMA16(af, bwp, acc[c]);
      }
    }
  }

  // ---- final store: rows w*16+g*4+i, all 384 cols ----
  float* outw = out + (size_t)b * (NTOK * DIM);
#pragma unroll
  for (int c = 0; c < 24; ++c) {
    int col = c * 16 + m16;
    float pbv = pb[col];
#pragma unroll
    for (int i = 0; i < 4; ++i) {
      int r = w * 16 + g * 4 + i;
      if (r < 49) outw[r * DIM + col] = acc[c][i] + pbv;
    }
  }
}

extern "C" void kernel_launch(void* const* d_in, const int* in_sizes, int n_in,
                              void* d_out, int out_size, void* d_ws, size_t ws_size,
                              hipStream_t stream) {
  const float* xe  = (const float*)d_in[0];
  const float* xb  = (const float*)d_in[1];
  const float* qw  = (const float*)d_in[2];
  const float* qb  = (const float*)d_in[3];
  const float* kvw = (const float*)d_in[4];
  const float* kvb = (const float*)d_in[5];
  const float* pw  = (const float*)d_in[6];
  const float* pb  = (const float*)d_in[7];
  const float* bt  = (const float*)d_in[8];
  float* out = (float*)d_out;
  short* wsS = (short*)d_ws;
  float* biasx = (float*)((char*)d_ws + BIAS_BYTE_OFF);

  const int nwin = in_sizes[0] / (NTOK * DIM);

  const int prep_items = 384 * 384 + 768 * 384 + 384 * 384 + HEADS * NTOK * NTOK;
  prep_kernel<<<(prep_items + 255) / 256, 256, 0, stream>>>(qw, kvw, pw, bt, wsS, biasx);

  hipFuncSetAttribute((const void*)fused_kernel,
                      hipFuncAttributeMaxDynamicSharedMemorySize, LDS_BYTES);
  fused_kernel<<<nwin, 256, LDS_BYTES, stream>>>(
      xe, xb, qb, kvb, pb,
      wsS + WQT_OFF, wsS + WKVT_OFF, wsS + WPT_OFF, biasx, out);
}

// Round 4
// 1596.589 us; speedup vs baseline: 1.3152x; 1.0068x over previous
//
#include <hip/hip_runtime.h>

#define NTOK 49
#define DIM 384
#define HEADS 12
#define SCALE 0.17677669529663687f

typedef __attribute__((ext_vector_type(8))) short bf16x8;
typedef __attribute__((ext_vector_type(4))) float f32x4;

#define MFMA16(a, b, c) __builtin_amdgcn_mfma_f32_16x16x32_bf16((a), (b), (c), 0, 0, 0)

__device__ __forceinline__ short f2bf(float f) {
  union { float f; unsigned u; } v; v.f = f;
  unsigned r = (v.u + 0x7FFFu + ((v.u >> 16) & 1u)) >> 16;
  return (short)(unsigned short)r;
}

// ws layout:
//   wqT  : short [384][384]      elem off 0
//   wkvT : short [768][384]      elem off 147456   (rows 0-383 = K, 384-767 = V)
//   wpT  : short [384][384]      elem off 442368
//   biasx: float [12][49][49]    byte off 1179648
#define WQT_OFF   0
#define WKVT_OFF  147456
#define WPT_OFF   442368
#define BIAS_BYTE_OFF 1179648

__global__ void prep_kernel(const float* __restrict__ qw, const float* __restrict__ kvw,
                            const float* __restrict__ pw, const float* __restrict__ bt,
                            short* __restrict__ wsS, float* __restrict__ biasx) {
  int id = blockIdx.x * 256 + threadIdx.x;
  const int SZ1 = 384 * 384;
  const int SZ2 = 768 * 384;
  const int SZ3 = 384 * 384;
  if (id < SZ1) {
    int n = id / 384, k = id % 384;
    wsS[WQT_OFF + id] = f2bf(qw[k * 384 + n]);
  } else if (id < SZ1 + SZ2) {
    int t = id - SZ1; int n = t / 384, k = t % 384;
    wsS[WKVT_OFF + t] = f2bf(kvw[k * 768 + n]);
  } else if (id < SZ1 + SZ2 + SZ3) {
    int t = id - (SZ1 + SZ2); int n = t / 384, k = t % 384;
    wsS[WPT_OFF + t] = f2bf(pw[k * 384 + n]);
  } else if (id < SZ1 + SZ2 + SZ3 + HEADS * NTOK * NTOK) {
    int t = id - (SZ1 + SZ2 + SZ3);
    int h = t / (NTOK * NTOK); int rc = t % (NTOK * NTOK);
    int r = rc / NTOK, c = rc % NTOK;
    int idx = ((r / 7 - c / 7) + 6) * 13 + ((r % 7 - c % 7) + 6);
    biasx[t] = bt[idx * HEADS + h];
  }
}

// LDS (shorts). All row strides multiple of 8 shorts (16B) for ds_read_b128
// alignment; chosen so b128 frag reads land at ≤2-way bank aliasing.
#define X_OFF    0                 // [49][392]
#define R_OFF    19208             // reuse region (20192 elems):
                                   //   phase1: per-wave Q scratch [16][104] x8 = 13312
#define KQH_OFF  (R_OFF)           // [64][72]
#define VT_OFF   (R_OFF + 4608)    // [64][72]  V^T: [vcol][token]
#define PS_OFF   (R_OFF + 9216)    // [2][49][72]  per-head P (hl stride 3528)
#define OH_OFF   (R_OFF + 16272)   // [2][49][40]  per-head O (hl stride 1960)
#define LDS_ELEMS 39400
#define LDS_BYTES (LDS_ELEMS * 2)  // 78800 -> 2 blocks/CU, 16 waves/CU

__global__ __launch_bounds__(512, 4)
void fused_kernel(const float* __restrict__ xe, const float* __restrict__ xb,
                  const float* __restrict__ qb, const float* __restrict__ kvb,
                  const float* __restrict__ pb,
                  const short* __restrict__ wqT, const short* __restrict__ wkvT,
                  const short* __restrict__ wpT, const float* __restrict__ biasx,
                  float* __restrict__ out) {
  extern __shared__ short lds[];
  short* X   = lds + X_OFF;
  short* KQH = lds + KQH_OFF;
  short* VT  = lds + VT_OFF;
  short* PSB = lds + PS_OFF;
  short* OHB = lds + OH_OFF;

  const int b   = blockIdx.x;
  const int tid = threadIdx.x;
  const int w   = tid >> 6;      // 0..7
  const int l   = tid & 63;
  const int m16 = l & 15;
  const int g   = l >> 4;
  const int hl  = w >> 2;        // head parity (attn)
  const int rt  = w & 3;         // row-tile (attn)

  short* QSC = lds + R_OFF + w * 1664;   // wave-local [16][104] Q scratch

  const f32x4 zf = {0.f, 0.f, 0.f, 0.f};

  // ---- stage x_edge into X (bf16, packed 8B writes) ----
  const float* xew = xe + (size_t)b * (NTOK * DIM);
  for (int i4 = tid; i4 < NTOK * DIM / 4; i4 += 512) {
    int e = i4 * 4;
    int r = e / DIM, c = e % DIM;
    float4 v = *(const float4*)(xew + e);
    ushort4 s;
    s.x = (unsigned short)f2bf(v.x); s.y = (unsigned short)f2bf(v.y);
    s.z = (unsigned short)f2bf(v.z); s.w = (unsigned short)f2bf(v.w);
    *(ushort4*)&X[r * 392 + c] = s;
  }
  __syncthreads();

  // ================= Phase 1: wave-local Q, two passes of 6 col-tiles ======
  // global tile t = p*6+tl, col-tile ctg = 4*(t>>1) + 2*hl + (t&1)
  // head j = 2*(t>>1)... pass p covers pair-indices j = 3p..3p+2 (h = 2j+hl)
  bf16x8 qf[6];
  {
    int ar = rt * 16 + m16; ar = ar < 49 ? ar : 48;
#pragma unroll
    for (int p = 0; p < 2; ++p) {
      f32x4 qacc[6];
#pragma unroll
      for (int tl = 0; tl < 6; ++tl) qacc[tl] = zf;
#pragma unroll
      for (int kk = 0; kk < 12; ++kk) {
        const int ko = kk * 32 + g * 8;
        bf16x8 ax = *(const bf16x8*)(&X[ar * 392 + ko]);
#pragma unroll
        for (int tl = 0; tl < 6; ++tl) {
          int t = p * 6 + tl;
          int ctg = 4 * (t >> 1) + 2 * hl + (t & 1);
          bf16x8 bw = *(const bf16x8*)(wqT + (size_t)(ctg * 16 + m16) * 384 + ko);
          qacc[tl] = MFMA16(ax, bw, qacc[tl]);
        }
      }
#pragma unroll
      for (int tl = 0; tl < 6; ++tl) {
        int t = p * 6 + tl;
        int ctg = 4 * (t >> 1) + 2 * hl + (t & 1);
        float qbv = qb[ctg * 16 + m16];
#pragma unroll
        for (int i = 0; i < 4; ++i)
          QSC[(g * 4 + i) * 104 + tl * 16 + m16] = f2bf((qacc[tl][i] + qbv) * SCALE);
      }
      asm volatile("s_waitcnt lgkmcnt(0)" ::: "memory");
      __builtin_amdgcn_sched_barrier(0);
#pragma unroll
      for (int jj = 0; jj < 3; ++jj)
        qf[p * 3 + jj] = *(const bf16x8*)(&QSC[m16 * 104 + jj * 32 + g * 8]);
      asm volatile("s_waitcnt lgkmcnt(0)" ::: "memory");  // reads done before pass-2 overwrite
      __builtin_amdgcn_sched_barrier(0);
    }
  }
  __syncthreads();   // all X(xe) reads + scratch use done

  // ---- stage x_body over X; zero V^T pad tokens once ----
  const float* xbw = xb + (size_t)b * (NTOK * DIM);
  for (int i4 = tid; i4 < NTOK * DIM / 4; i4 += 512) {
    int e = i4 * 4;
    int r = e / DIM, c = e % DIM;
    float4 v = *(const float4*)(xbw + e);
    ushort4 s;
    s.x = (unsigned short)f2bf(v.x); s.y = (unsigned short)f2bf(v.y);
    s.z = (unsigned short)f2bf(v.z); s.w = (unsigned short)f2bf(v.w);
    *(ushort4*)&X[r * 392 + c] = s;
  }
  for (int i = tid; i < 64 * 15; i += 512) {
    int d = i / 15, t2 = 49 + i % 15;
    VT[d * 72 + t2] = 0;
  }
  __syncthreads();

  // ================= Phase 3: per-pair KV GEMM + attention + fused proj =====
  f32x4 acc[3][4];
#pragma unroll
  for (int c = 0; c < 3; ++c)
#pragma unroll
    for (int m = 0; m < 4; ++m) acc[c][m] = zf;

  // KV-gemm roles
  const int kvh = w >> 2;          // 0 = K, 1 = V
  const int c32 = (w >> 1) & 1;    // col-32 half
  const int r32 = w & 1;           // row-32 half

#pragma unroll
  for (int j = 0; j < 6; ++j) {
    // ---- KV GEMM: wave computes 32 cols (c32) x 32 rows (r32) of K or V ----
    {
      f32x4 kva[2][2];
#pragma unroll
      for (int ct = 0; ct < 2; ++ct)
#pragma unroll
        for (int m = 0; m < 2; ++m) kva[ct][m] = zf;
      const short* bp = wkvT + (size_t)(kvh * 384 + j * 64 + c32 * 32) * 384;
#pragma unroll
      for (int kk = 0; kk < 12; ++kk) {
        const int ko = kk * 32 + g * 8;
        bf16x8 b0 = *(const bf16x8*)(bp + (size_t)(m16) * 384 + ko);
        bf16x8 b1 = *(const bf16x8*)(bp + (size_t)(16 + m16) * 384 + ko);
#pragma unroll
        for (int m = 0; m < 2; ++m) {
          int ar = (r32 * 2 + m) * 16 + m16; ar = ar < 49 ? ar : 48;
          bf16x8 ax = *(const bf16x8*)(&X[ar * 392 + ko]);
          kva[0][m] = MFMA16(ax, b0, kva[0][m]);
          kva[1][m] = MFMA16(ax, b1, kva[1][m]);
        }
      }
      const int cbase = kvh * 384 + j * 64 + c32 * 32;
      if (kvh == 0) {
#pragma unroll
        for (int ct = 0; ct < 2; ++ct) {
          float kb_ = kvb[cbase + ct * 16 + m16];
          int cl = c32 * 32 + ct * 16 + m16;
#pragma unroll
          for (int m = 0; m < 2; ++m)
#pragma unroll
            for (int i = 0; i < 4; ++i) {
              int r = (r32 * 2 + m) * 16 + g * 4 + i;
              KQH[r * 72 + cl] = f2bf(kva[ct][m][i] + kb_);
            }
        }
      } else {
#pragma unroll
        for (int ct = 0; ct < 2; ++ct) {
          float vb_ = kvb[cbase + ct * 16 + m16];
          int cl = c32 * 32 + ct * 16 + m16;
#pragma unroll
          for (int m = 0; m < 2; ++m)
#pragma unroll
            for (int i = 0; i < 4; ++i) {
              int r = (r32 * 2 + m) * 16 + g * 4 + i;
              if (r < 49) VT[cl * 72 + r] = f2bf(kva[ct][m][i] + vb_);
            }
        }
      }
    }
    __syncthreads();   // KQH/VT ready (also fences prev-j proj reads of OHB)

    // ---- attention: wave (hl, rt) does head h = 2j+hl, query rows rt*16.. ----
    {
      const int h = 2 * j + hl;
      float bv4[4][4];
#pragma unroll
      for (int i = 0; i < 4; ++i) {
        int row = rt * 16 + g * 4 + i; row = row < 49 ? row : 48;
#pragma unroll
        for (int t = 0; t < 4; ++t) {
          int c = t * 16 + m16; c = c < 49 ? c : 48;
          bv4[i][t] = biasx[(h * NTOK + row) * NTOK + c];
        }
      }
      f32x4 s[4];
#pragma unroll
      for (int t = 0; t < 4; ++t) {
        bf16x8 bk = *(const bf16x8*)(&KQH[(t * 16 + m16) * 72 + hl * 32 + g * 8]);
        s[t] = MFMA16(qf[j], bk, zf);
      }
      short* PS = PSB + hl * 3528;
#pragma unroll
      for (int i = 0; i < 4; ++i) {
        const int row = rt * 16 + g * 4 + i;
        float sv[4];
#pragma unroll
        for (int t = 0; t < 4; ++t) {
          int c = t * 16 + m16;
          sv[t] = (row < 49 && c < 49) ? s[t][i] + bv4[i][t] : -INFINITY;
        }
        float mx = fmaxf(fmaxf(sv[0], sv[1]), fmaxf(sv[2], sv[3]));
#pragma unroll
        for (int d = 1; d < 16; d <<= 1) mx = fmaxf(mx, __shfl_xor(mx, d, 16));
        float mxr = fmaxf(mx, -3.0e38f);
        float e0 = __expf(sv[0] - mxr), e1 = __expf(sv[1] - mxr);
        float e2 = __expf(sv[2] - mxr), e3 = __expf(sv[3] - mxr);
        float sum = e0 + e1 + e2 + e3;
#pragma unroll
        for (int d = 1; d < 16; d <<= 1) sum += __shfl_xor(sum, d, 16);
        if (row < 49) {
          float inv = 1.0f / sum;
          PS[row * 72 +  0 + m16] = f2bf(e0 * inv);
          PS[row * 72 + 16 + m16] = f2bf(e1 * inv);
          PS[row * 72 + 32 + m16] = f2bf(e2 * inv);
          PS[row * 72 + 48 + m16] = f2bf(e3 * inv);
        }
      }
      asm volatile("s_waitcnt lgkmcnt(0)" ::: "memory");
      __builtin_amdgcn_sched_barrier(0);

      int arow = rt * 16 + m16; arow = arow < 49 ? arow : 48;
      f32x4 o0 = zf, o1 = zf;
#pragma unroll
      for (int ks = 0; ks < 2; ++ks) {
        bf16x8 ap  = *(const bf16x8*)(&PS[arow * 72 + ks * 32 + g * 8]);
        bf16x8 vb0 = *(const bf16x8*)(&VT[(hl * 32 + m16) * 72 + ks * 32 + g * 8]);
        bf16x8 vb1 = *(const bf16x8*)(&VT[(hl * 32 + 16 + m16) * 72 + ks * 32 + g * 8]);
        o0 = MFMA16(ap, vb0, o0);
        o1 = MFMA16(ap, vb1, o1);
      }
      short* OH = OHB + hl * 1960;
#pragma unroll
      for (int i = 0; i < 4; ++i) {
        int r = rt * 16 + g * 4 + i;
        if (r < 49) {
          OH[r * 40 + m16]      = f2bf(o0[i]);
          OH[r * 40 + 16 + m16] = f2bf(o1[i]);
        }
      }
    }
    __syncthreads();   // OH ready for proj

    // ---- fused out-projection: wave owns col-tiles w*3..w*3+2, all rows ----
#pragma unroll
    for (int h2 = 0; h2 < 2; ++h2) {
      bf16x8 af[4];
#pragma unroll
      for (int m = 0; m < 4; ++m) {
        int arw = m * 16 + m16; arw = arw < 49 ? arw : 48;
        af[m] = *(const bf16x8*)(&OHB[h2 * 1960 + arw * 40 + g * 8]);
      }
#pragma unroll
      for (int c = 0; c < 3; ++c) {
        int ctg = w * 3 + c;
        bf16x8 bwp = *(const bf16x8*)(wpT + (size_t)(ctg * 16 + m16) * 384 +
                                      (2 * j + h2) * 32 + g * 8);
#pragma unroll
        for (int m = 0; m < 4; ++m) acc[c][m] = MFMA16(af[m], bwp, acc[c][m]);
      }
    }
    // no barrier: next iteration's post-KV __syncthreads orders these proj
    // reads before the next OH/KQH/VT overwrites
  }

  // ---- final store: wave covers cols (w*3..w*3+2)*16, all 49 rows ----
  float* outw = out + (size_t)b * (NTOK * DIM);
#pragma unroll
  for (int c = 0; c < 3; ++c) {
    int col = (w * 3 + c) * 16 + m16;
    float pbv = pb[col];
#pragma unroll
    for (int m = 0; m < 4; ++m)
#pragma unroll
      for (int i = 0; i < 4; ++i) {
        int r = m * 16 + g * 4 + i;
        if (r < 49) outw[r * DIM + col] = acc[c][m][i] + pbv;
      }
  }
}

extern "C" void kernel_launch(void* const* d_in, const int* in_sizes, int n_in,
                              void* d_out, int out_size, void* d_ws, size_t ws_size,
                              hipStream_t stream) {
  const float* xe  = (const float*)d_in[0];
  const float* xb  = (const float*)d_in[1];
  const float* qw  = (const float*)d_in[2];
  const float* qb  = (const float*)d_in[3];
  const float* kvw = (const float*)d_in[4];
  const float* kvb = (const float*)d_in[5];
  const float* pw  = (const float*)d_in[6];
  const float* pb  = (const float*)d_in[7];
  const float* bt  = (const float*)d_in[8];
  float* out = (float*)d_out;
  short* wsS = (short*)d_ws;
  float* biasx = (float*)((char*)d_ws + BIAS_BYTE_OFF);

  const int nwin = in_sizes[0] / (NTOK * DIM);

  const int prep_items = 384 * 384 + 768 * 384 + 384 * 384 + HEADS * NTOK * NTOK;
  prep_kernel<<<(prep_items + 255) / 256, 256, 0, stream>>>(qw, kvw, pw, bt, wsS, biasx);

  hipFuncSetAttribute((const void*)fused_kernel,
                      hipFuncAttributeMaxDynamicSharedMemorySize, LDS_BYTES);
  fused_kernel<<<nwin, 512, LDS_BYTES, stream>>>(
      xe, xb, qb, kvb, pb,
      wsS + WQT_OFF, wsS + WKVT_OFF, wsS + WPT_OFF, biasx, out);
}